// Round 3
// baseline (433.913 us; speedup 1.0000x reference)
//
#include <hip/hip_runtime.h>
#include <hip/hip_fp16.h>
#include <stdint.h>

typedef _Float16 half8 __attribute__((ext_vector_type(8)));
typedef _Float16 half4v __attribute__((ext_vector_type(4)));
typedef float floatx4 __attribute__((ext_vector_type(4)));

// ---------------------------------------------------------------------------
// async global->LDS copy, 16B per lane. LDS dest = wave-uniform base + lane*16.
__device__ inline void gload_lds16(const void* g, void* l) {
    __builtin_amdgcn_global_load_lds(
        (const __attribute__((address_space(1))) uint32_t*)g,
        (__attribute__((address_space(3))) uint32_t*)l, 16, 0, 0);
}

// ---------------------------------------------------------------------------
// f32 -> A-style split cat [hi | lo | hi], out row stride 3*nc.
// Markidis 3-term: [a_hi|a_lo|a_hi] . [b_hi|b_hi|b_lo] = hh + lh + hl.
__global__ __launch_bounds__(256) void split_cast_a(
    const float* __restrict__ in, _Float16* __restrict__ out, int nc, int n) {
    int i = (blockIdx.x * 256 + threadIdx.x) * 4;
    if (i >= n) return;
    float4 v = *(const float4*)(in + i);
    int r = i / nc, c = i % nc;
    half4v hi, lo;
    hi[0] = (_Float16)v.x; lo[0] = (_Float16)(v.x - (float)hi[0]);
    hi[1] = (_Float16)v.y; lo[1] = (_Float16)(v.y - (float)hi[1]);
    hi[2] = (_Float16)v.z; lo[2] = (_Float16)(v.z - (float)hi[2]);
    hi[3] = (_Float16)v.w; lo[3] = (_Float16)(v.w - (float)hi[3]);
    size_t base = (size_t)r * 3 * nc;
    *(half4v*)(out + base + c) = hi;
    *(half4v*)(out + base + nc + c) = lo;
    *(half4v*)(out + base + 2 * nc + c) = hi;
}

// ---------------------------------------------------------------------------
// transpose + B-style split cat [hi | hi | lo]: out[n][...]=f(in[k][n]).
__global__ __launch_bounds__(256) void transpose_split_b(
    const float* __restrict__ in, _Float16* __restrict__ out, int dim) {
    __shared__ float tile[32][33];
    const int tx = threadIdx.x, ty = threadIdx.y;
    const int bx = blockIdx.x * 32, by = blockIdx.y * 32;
#pragma unroll
    for (int i = 0; i < 32; i += 8)
        tile[ty + i][tx] = in[(size_t)(by + ty + i) * dim + bx + tx];
    __syncthreads();
#pragma unroll
    for (int i = 0; i < 32; i += 8) {
        float v = tile[tx][ty + i];
        _Float16 hi = (_Float16)v;
        _Float16 lo = (_Float16)(v - (float)hi);
        size_t o = (size_t)(bx + ty + i) * 3 * dim + by + tx;
        out[o] = hi;
        out[o + dim] = hi;
        out[o + 2 * dim] = lo;
    }
}

// ---------------------------------------------------------------------------
// C = A @ B^T.  A: [M][lda] f16 (K used), B: [N][ldb] f16.
// 128x128 tile, BK=64, 4 waves (2x2), each wave 64x64 via 4x4 mfma 16x16x32.
// LDS XOR swizzle: 16B chunk c of row r at physical chunk c ^ (r&7), via
// pre-swizzled per-lane GLOBAL source (rule #21: both-sides-or-neither).
// OMODE: 1 = f16 out transposed C[n][m] (stride M);
//        3 = f32 out C[m][n] * cscale;
//        4 = A-style split out [hi|lo|hi], row stride 3N;
//        5 = B-style split out [hi|hi|lo], row stride 3N.
template <int OMODE>
__global__ __launch_bounds__(256) void gemm_bt(
    const _Float16* __restrict__ A, const _Float16* __restrict__ B,
    void* __restrict__ Cout, int M, int N, int K, int lda, int ldb,
    float cscale) {
    __shared__ _Float16 As[128 * 64];
    __shared__ _Float16 Bs[128 * 64];

    const int tid  = threadIdx.x;
    const int lane = tid & 63;
    const int wid  = tid >> 6;
    const int wr   = wid >> 1;
    const int wc   = wid & 1;
    const int row0 = blockIdx.y * 128;
    const int col0 = blockIdx.x * 128;

    floatx4 acc[4][4] = {};

    const int srow   = lane >> 3;              // 0..7
    const int schunk = (lane & 7) ^ srow;      // source-side XOR swizzle
    const char* gA = (const char*)(A + (size_t)(row0 + wid * 8 + srow) * lda) + schunk * 16;
    const char* gB = (const char*)(B + (size_t)(col0 + wid * 8 + srow) * ldb) + schunk * 16;
    char* lA = (char*)As + (wid * 8) * 128;
    char* lB = (char*)Bs + (wid * 8) * 128;

    const int frow   = lane & 15;
    const int rxor   = frow & 7;
    const int kchunk = lane >> 4;              // 0..3

    const int kTiles = K >> 6;
    for (int kt = 0; kt < kTiles; ++kt) {
        const size_t kb = (size_t)(kt << 6) * 2;
#pragma unroll
        for (int r = 0; r < 4; ++r) {
            gload_lds16(gA + (size_t)(r * 32) * lda * 2 + kb, lA + r * 32 * 128);
            gload_lds16(gB + (size_t)(r * 32) * ldb * 2 + kb, lB + r * 32 * 128);
        }
        __syncthreads();
#pragma unroll
        for (int kk = 0; kk < 2; ++kk) {
            half8 af[4], bf[4];
            const int pc = ((kk * 4 + kchunk) ^ rxor) * 16;
#pragma unroll
            for (int mi = 0; mi < 4; ++mi)
                af[mi] = *(const half8*)((const char*)As + (wr * 64 + mi * 16 + frow) * 128 + pc);
#pragma unroll
            for (int ni = 0; ni < 4; ++ni)
                bf[ni] = *(const half8*)((const char*)Bs + (wc * 64 + ni * 16 + frow) * 128 + pc);
#pragma unroll
            for (int mi = 0; mi < 4; ++mi)
#pragma unroll
                for (int ni = 0; ni < 4; ++ni)
                    acc[mi][ni] = __builtin_amdgcn_mfma_f32_16x16x32_f16(
                        af[mi], bf[ni], acc[mi][ni], 0, 0, 0);
        }
        __syncthreads();
    }

    // epilogue: D row = 4*(lane>>4)+j, col = lane&15  (m89-verified layout)
    const int orow0 = row0 + wr * 64 + ((lane >> 4) << 2);
    const int ocol0 = col0 + wc * 64 + (lane & 15);
#pragma unroll
    for (int mi = 0; mi < 4; ++mi) {
#pragma unroll
        for (int ni = 0; ni < 4; ++ni) {
#pragma unroll
            for (int j = 0; j < 4; ++j) {
                const int rr = orow0 + mi * 16 + j;
                const int cc = ocol0 + ni * 16;
                const float v = acc[mi][ni][j] * cscale;
                if (OMODE == 1) {
                    ((_Float16*)Cout)[(size_t)cc * M + rr] = (_Float16)v;
                } else if (OMODE == 3) {
                    ((float*)Cout)[(size_t)rr * N + cc] = v;
                } else {
                    _Float16 hi = (_Float16)v;
                    _Float16 lo = (_Float16)(v - (float)hi);
                    _Float16* o = (_Float16*)Cout + (size_t)rr * 3 * N + cc;
                    if (OMODE == 4) {            // A-style [hi|lo|hi]
                        o[0] = hi; o[N] = lo; o[2 * N] = hi;
                    } else {                     // 5: B-style [hi|hi|lo]
                        o[0] = hi; o[N] = hi; o[2 * N] = lo;
                    }
                }
            }
        }
    }
}

// ---------------------------------------------------------------------------
// row softmax over f32 S (already scaled /32), in place: writes normalized
// P = exp(s-m)/sum as f16 at the same row base (row stride ncols f32 slots).
__global__ __launch_bounds__(256) void softmax_inplace(
    float* __restrict__ S, int ncols) {
    const int row = blockIdx.x;
    float* srow = S + (size_t)row * ncols;
    const int t = threadIdx.x;

    float x[16];
#pragma unroll
    for (int q = 0; q < 4; ++q) {
        float4 v = *(float4*)(srow + t * 16 + q * 4);
        x[q * 4 + 0] = v.x; x[q * 4 + 1] = v.y;
        x[q * 4 + 2] = v.z; x[q * 4 + 3] = v.w;
    }
    float m = x[0];
#pragma unroll
    for (int j = 1; j < 16; ++j) m = fmaxf(m, x[j]);
#pragma unroll
    for (int off = 32; off; off >>= 1) m = fmaxf(m, __shfl_xor(m, off));
    __shared__ float redm[4];
    if ((t & 63) == 0) redm[t >> 6] = m;
    __syncthreads();
    m = fmaxf(fmaxf(redm[0], redm[1]), fmaxf(redm[2], redm[3]));

    float s = 0.0f;
#pragma unroll
    for (int j = 0; j < 16; ++j) {
        x[j] = __expf(x[j] - m);
        s += x[j];
    }
#pragma unroll
    for (int off = 32; off; off >>= 1) s += __shfl_xor(s, off);
    __shared__ float reds[4];
    if ((t & 63) == 0) reds[t >> 6] = s;
    __syncthreads();
    s = reds[0] + reds[1] + reds[2] + reds[3];
    const float inv = 1.0f / s;

    _Float16* prow = (_Float16*)srow;
    half8 o0, o1;
#pragma unroll
    for (int j = 0; j < 8; ++j) {
        o0[j] = (_Float16)(x[j] * inv);
        o1[j] = (_Float16)(x[8 + j] * inv);
    }
    __syncthreads();   // all f32 reads of this row complete before overwrite
    *(half8*)(prow + t * 16)     = o0;
    *(half8*)(prow + t * 16 + 8) = o1;
}

// ---------------------------------------------------------------------------
extern "C" void kernel_launch(void* const* d_in, const int* in_sizes, int n_in,
                              void* d_out, int out_size, void* d_ws, size_t ws_size,
                              hipStream_t stream) {
    const float* x1 = (const float*)d_in[0];   // [4096][1024]
    const float* x2 = (const float*)d_in[1];   // [4096][1024]
    const float* Wq = (const float*)d_in[2];   // [1024][1024]
    const float* Wk = (const float*)d_in[3];
    const float* Wv = (const float*)d_in[4];
    float* out = (float*)d_out;                // [4096][1024] f32

    const int NQ = 4096, NKV = 4096, D = 1024;

    // workspace layout (MB).  S (0..64) overlays buffers that are dead by
    // the time the scores GEMM runs (stream-ordered, single stream).
    char* ws = (char*)d_ws;
    float*    S     = (float*)ws;                       //   0..64  f32 scores -> f16 P
    _Float16* x1cat = (_Float16*)(ws);                  //   0..24  [4096][3072] A-style
    _Float16* x2cat = (_Float16*)(ws + (24u  << 20));   //  24..48  [4096][3072] A-style
    _Float16* Wqct  = (_Float16*)(ws + (48u  << 20));   //  48..54  [1024][3072] B-style
    _Float16* Wkct  = (_Float16*)(ws + (54u  << 20));   //  54..60
    _Float16* Wvct  = (_Float16*)(ws + (60u  << 20));   //  60..66
    _Float16* Qcat  = (_Float16*)(ws + (66u  << 20));   //  66..90  [4096][3072] A-style
    _Float16* Kcat  = (_Float16*)(ws + (90u  << 20));   //  90..114 [4096][3072] B-style
    _Float16* Vt    = (_Float16*)(ws + (114u << 20));   // 114..122 [1024][4096] f16

    // 1) split casts + split transposes (Markidis 3-segment, K=3072)
    split_cast_a<<<(NQ * D) / 1024, 256, 0, stream>>>(x1, x1cat, D, NQ * D);
    split_cast_a<<<(NKV * D) / 1024, 256, 0, stream>>>(x2, x2cat, D, NKV * D);
    dim3 tb(32, 8), tg(D / 32, D / 32);
    transpose_split_b<<<tg, tb, 0, stream>>>(Wq, Wqct, D);
    transpose_split_b<<<tg, tb, 0, stream>>>(Wk, Wkct, D);
    transpose_split_b<<<tg, tb, 0, stream>>>(Wv, Wvct, D);

    // 2) projections at K=3072.  Q emits A-style split, K emits B-style
    //    split (for the scores GEMM); V emits f16 transposed [D][NKV].
    gemm_bt<4><<<dim3(D / 128, NQ  / 128), 256, 0, stream>>>(x1cat, Wqct, Qcat, NQ,  D, 3 * D, 3 * D, 3 * D, 1.0f);
    gemm_bt<5><<<dim3(D / 128, NKV / 128), 256, 0, stream>>>(x2cat, Wkct, Kcat, NKV, D, 3 * D, 3 * D, 3 * D, 1.0f);
    gemm_bt<1><<<dim3(D / 128, NKV / 128), 256, 0, stream>>>(x2cat, Wvct, Vt,   NKV, D, 3 * D, 3 * D, 3 * D, 1.0f);

    // 3) scores f32: S = (Qcat @ Kcat^T)/32 at K=3072 (hh + lh + hl terms)
    gemm_bt<3><<<dim3(NKV / 128, NQ / 128), 256, 0, stream>>>(Qcat, Kcat, S, NQ, NKV, 3 * D, 3 * D, 3 * D, 1.0f / 32.0f);

    // 4) softmax rows in place: f32 scores -> normalized f16 P (stride 8192 f16)
    softmax_inplace<<<NQ, 256, 0, stream>>>(S, NKV);

    // 5) out = P @ V  (A = P f16, lda=8192; B^T = Vt[D][NKV], ldb=4096)
    gemm_bt<3><<<dim3(D / 128, NQ / 128), 256, 0, stream>>>((const _Float16*)S, Vt, out, NQ, D, NKV, 2 * NKV, NKV, 1.0f);
}

// Round 4
// 413.768 us; speedup vs baseline: 1.0487x; 1.0487x over previous
//
#include <hip/hip_runtime.h>
#include <hip/hip_fp16.h>
#include <stdint.h>

typedef _Float16 half8 __attribute__((ext_vector_type(8)));
typedef _Float16 half4v __attribute__((ext_vector_type(4)));
typedef float floatx4 __attribute__((ext_vector_type(4)));

// ---------------------------------------------------------------------------
// async global->LDS copy, 16B per lane. LDS dest = wave-uniform base + lane*16.
__device__ inline void gload_lds16(const void* g, void* l) {
    __builtin_amdgcn_global_load_lds(
        (const __attribute__((address_space(1))) uint32_t*)g,
        (__attribute__((address_space(3))) uint32_t*)l, 16, 0, 0);
}

// ---------------------------------------------------------------------------
// f32 -> A-style split cat [hi | lo | hi], out row stride 3*nc.
// Markidis 3-term: [a_hi|a_lo|a_hi] . [b_hi|b_hi|b_lo] = hh + lh + hl.
__global__ __launch_bounds__(256) void split_cast_a(
    const float* __restrict__ in, _Float16* __restrict__ out, int nc, int n) {
    int i = (blockIdx.x * 256 + threadIdx.x) * 4;
    if (i >= n) return;
    float4 v = *(const float4*)(in + i);
    int r = i / nc, c = i % nc;
    half4v hi, lo;
    hi[0] = (_Float16)v.x; lo[0] = (_Float16)(v.x - (float)hi[0]);
    hi[1] = (_Float16)v.y; lo[1] = (_Float16)(v.y - (float)hi[1]);
    hi[2] = (_Float16)v.z; lo[2] = (_Float16)(v.z - (float)hi[2]);
    hi[3] = (_Float16)v.w; lo[3] = (_Float16)(v.w - (float)hi[3]);
    size_t base = (size_t)r * 3 * nc;
    *(half4v*)(out + base + c) = hi;
    *(half4v*)(out + base + nc + c) = lo;
    *(half4v*)(out + base + 2 * nc + c) = hi;
}

// ---------------------------------------------------------------------------
// transpose + B-style split cat [hi | hi | lo]: out[n][...]=f(in[k][n]).
__global__ __launch_bounds__(256) void transpose_split_b(
    const float* __restrict__ in, _Float16* __restrict__ out, int dim) {
    __shared__ float tile[32][33];
    const int tx = threadIdx.x, ty = threadIdx.y;
    const int bx = blockIdx.x * 32, by = blockIdx.y * 32;
#pragma unroll
    for (int i = 0; i < 32; i += 8)
        tile[ty + i][tx] = in[(size_t)(by + ty + i) * dim + bx + tx];
    __syncthreads();
#pragma unroll
    for (int i = 0; i < 32; i += 8) {
        float v = tile[tx][ty + i];
        _Float16 hi = (_Float16)v;
        _Float16 lo = (_Float16)(v - (float)hi);
        size_t o = (size_t)(bx + ty + i) * 3 * dim + by + tx;
        out[o] = hi;
        out[o + dim] = hi;
        out[o + 2 * dim] = lo;
    }
}

// ---------------------------------------------------------------------------
// 128x128-tile GEMM (verified): C = A @ B^T. OMODE 1/3/4/5 as before.
template <int OMODE>
__global__ __launch_bounds__(256) void gemm_bt(
    const _Float16* __restrict__ A, const _Float16* __restrict__ B,
    void* __restrict__ Cout, int M, int N, int K, int lda, int ldb,
    float cscale) {
    __shared__ _Float16 As[128 * 64];
    __shared__ _Float16 Bs[128 * 64];

    const int tid  = threadIdx.x;
    const int lane = tid & 63;
    const int wid  = tid >> 6;
    const int wr   = wid >> 1;
    const int wc   = wid & 1;
    const int row0 = blockIdx.y * 128;
    const int col0 = blockIdx.x * 128;

    floatx4 acc[4][4] = {};

    const int srow   = lane >> 3;
    const int schunk = (lane & 7) ^ srow;      // source-side XOR swizzle
    const char* gA = (const char*)(A + (size_t)(row0 + wid * 8 + srow) * lda) + schunk * 16;
    const char* gB = (const char*)(B + (size_t)(col0 + wid * 8 + srow) * ldb) + schunk * 16;
    char* lA = (char*)As + (wid * 8) * 128;
    char* lB = (char*)Bs + (wid * 8) * 128;

    const int frow   = lane & 15;
    const int rxor   = frow & 7;
    const int kchunk = lane >> 4;

    const int kTiles = K >> 6;
    for (int kt = 0; kt < kTiles; ++kt) {
        const size_t kb = (size_t)(kt << 6) * 2;
#pragma unroll
        for (int r = 0; r < 4; ++r) {
            gload_lds16(gA + (size_t)(r * 32) * lda * 2 + kb, lA + r * 32 * 128);
            gload_lds16(gB + (size_t)(r * 32) * ldb * 2 + kb, lB + r * 32 * 128);
        }
        __syncthreads();
#pragma unroll
        for (int kk = 0; kk < 2; ++kk) {
            half8 af[4], bf[4];
            const int pc = ((kk * 4 + kchunk) ^ rxor) * 16;
#pragma unroll
            for (int mi = 0; mi < 4; ++mi)
                af[mi] = *(const half8*)((const char*)As + (wr * 64 + mi * 16 + frow) * 128 + pc);
#pragma unroll
            for (int ni = 0; ni < 4; ++ni)
                bf[ni] = *(const half8*)((const char*)Bs + (wc * 64 + ni * 16 + frow) * 128 + pc);
#pragma unroll
            for (int mi = 0; mi < 4; ++mi)
#pragma unroll
                for (int ni = 0; ni < 4; ++ni)
                    acc[mi][ni] = __builtin_amdgcn_mfma_f32_16x16x32_f16(
                        af[mi], bf[ni], acc[mi][ni], 0, 0, 0);
        }
        __syncthreads();
    }

    const int orow0 = row0 + wr * 64 + ((lane >> 4) << 2);
    const int ocol0 = col0 + wc * 64 + (lane & 15);
#pragma unroll
    for (int mi = 0; mi < 4; ++mi) {
#pragma unroll
        for (int ni = 0; ni < 4; ++ni) {
#pragma unroll
            for (int j = 0; j < 4; ++j) {
                const int rr = orow0 + mi * 16 + j;
                const int cc = ocol0 + ni * 16;
                const float v = acc[mi][ni][j] * cscale;
                if (OMODE == 1) {
                    ((_Float16*)Cout)[(size_t)cc * M + rr] = (_Float16)v;
                } else if (OMODE == 3) {
                    ((float*)Cout)[(size_t)rr * N + cc] = v;
                } else {
                    _Float16 hi = (_Float16)v;
                    _Float16 lo = (_Float16)(v - (float)hi);
                    _Float16* o = (_Float16*)Cout + (size_t)rr * 3 * N + cc;
                    if (OMODE == 4) { o[0] = hi; o[N] = lo; o[2 * N] = hi; }
                    else            { o[0] = hi; o[N] = hi; o[2 * N] = lo; }
                }
            }
        }
    }
}

// ---------------------------------------------------------------------------
// 256x256-tile, BK=64, 8-wave (2Mx4N), 8-phase-class schedule with counted
// vmcnt (T2+T3+T4+T5).  f32 output * cscale.  M,N % 256 == 0, K % 64 == 0.
// Per K-tile: 4 phases {reads -> barrier -> lgkmcnt(0) -> prio MFMA -> barrier};
// phase 3 stages tile t+2 after all reads of buf[d] completed, then vmcnt(8)
// guarantees tile t+1 resident before the closing barrier.
#define SB0() __builtin_amdgcn_sched_barrier(0)

#define PH_READS(KK, MH, DO_B)                                                \
    {                                                                         \
        const int pc_ = (((KK) * 4 + kchunk) ^ rxor) * 16;                    \
        if (DO_B) {                                                           \
            _Pragma("unroll")                                                 \
            for (int ni = 0; ni < 4; ++ni)                                    \
                bf[ni] = *(const half8*)(bsB + (wc * 64 + ni * 16 + frow) * 128 + pc_); \
        }                                                                     \
        _Pragma("unroll")                                                     \
        for (int mi = 0; mi < 4; ++mi)                                        \
            af[mi] = *(const half8*)(bsA + (wr * 128 + ((MH) * 4 + mi) * 16 + frow) * 128 + pc_); \
    }

#define PH_MFMA(MH)                                                           \
    __builtin_amdgcn_s_setprio(1);                                            \
    _Pragma("unroll")                                                         \
    for (int mi = 0; mi < 4; ++mi)                                            \
        _Pragma("unroll")                                                     \
        for (int ni = 0; ni < 4; ++ni)                                        \
            acc[(MH) * 4 + mi][ni] = __builtin_amdgcn_mfma_f32_16x16x32_f16(  \
                af[mi], bf[ni], acc[(MH) * 4 + mi][ni], 0, 0, 0);             \
    __builtin_amdgcn_s_setprio(0);

__global__ __launch_bounds__(512, 2) void gemm256_bt_f32(
    const _Float16* __restrict__ A, const _Float16* __restrict__ B,
    float* __restrict__ C, int M, int N, int K, int lda, int ldb,
    float cscale) {
    __shared__ _Float16 As[2][256 * 64];   // 2 x 32 KiB
    __shared__ _Float16 Bs[2][256 * 64];   // 2 x 32 KiB  (total 128 KiB)

    const int tid  = threadIdx.x;
    const int lane = tid & 63;
    const int wid  = tid >> 6;     // 0..7
    const int wr   = wid >> 2;     // 0..1  M-half
    const int wc   = wid & 3;      // 0..3  N-quarter
    const int row0 = blockIdx.y * 256;
    const int col0 = blockIdx.x * 256;

    floatx4 acc[8][4] = {};

    // staging: instr i covers rows [wid*8 + i*64 .. +7]; lane>>3=row, lane&7=chunk
    const int srow   = lane >> 3;
    const int schunk = (lane & 7) ^ srow;    // pre-swizzled global source
    const _Float16* gA = A + (size_t)(row0 + wid * 8 + srow) * lda + schunk * 8;
    const _Float16* gB = B + (size_t)(col0 + wid * 8 + srow) * ldb + schunk * 8;

    const int frow   = lane & 15;
    const int rxor   = frow & 7;
    const int kchunk = lane >> 4;

    const int NT = K >> 6;

    auto STAGE = [&](char* lA, char* lB, int t) {
#pragma unroll
        for (int i = 0; i < 4; ++i) {
            gload_lds16(gA + (size_t)(i * 64) * lda + (size_t)t * 64,
                        lA + (wid * 8 + i * 64) * 128);
            gload_lds16(gB + (size_t)(i * 64) * ldb + (size_t)t * 64,
                        lB + (wid * 8 + i * 64) * 128);
        }
    };

    // prologue: stage tiles 0 and 1; wait tile 0 (8 youngest still allowed)
    STAGE((char*)As[0], (char*)Bs[0], 0);
    if (NT > 1) STAGE((char*)As[1], (char*)Bs[1], 1);
    asm volatile("s_waitcnt vmcnt(8)" ::: "memory");
    SB0();
    __builtin_amdgcn_s_barrier();

    half8 af[4], bf[4];
    for (int t = 0; t < NT; ++t) {
        const int d = t & 1;
        const char* bsA = (const char*)As[0] + d * (256 * 64 * 2);
        const char* bsB = (const char*)Bs[0] + d * (256 * 64 * 2);

        // ---- phase 0: kk=0, M-half 0 (+ B for kk=0)
        PH_READS(0, 0, true)
        SB0();
        __builtin_amdgcn_s_barrier();
        asm volatile("s_waitcnt lgkmcnt(0)" ::: "memory");
        SB0();
        PH_MFMA(0)
        __builtin_amdgcn_s_barrier();

        // ---- phase 1: kk=0, M-half 1
        PH_READS(0, 1, false)
        SB0();
        __builtin_amdgcn_s_barrier();
        asm volatile("s_waitcnt lgkmcnt(0)" ::: "memory");
        SB0();
        PH_MFMA(1)
        __builtin_amdgcn_s_barrier();

        // ---- phase 2: kk=1, M-half 0 (+ B for kk=1)
        PH_READS(1, 0, true)
        SB0();
        __builtin_amdgcn_s_barrier();
        asm volatile("s_waitcnt lgkmcnt(0)" ::: "memory");
        SB0();
        PH_MFMA(0)
        __builtin_amdgcn_s_barrier();

        // ---- phase 3: kk=1, M-half 1; stage t+2; counted vmcnt
        PH_READS(1, 1, false)
        asm volatile("s_waitcnt lgkmcnt(0)" ::: "memory");  // my reads done
        SB0();
        __builtin_amdgcn_s_barrier();                       // ALL reads of buf[d] done
        if (t + 2 < NT) {
            STAGE((char*)As[0] + d * (256 * 64 * 2),
                  (char*)Bs[0] + d * (256 * 64 * 2), t + 2);
            asm volatile("s_waitcnt vmcnt(8)" ::: "memory"); // tile t+1 landed
        } else {
            asm volatile("s_waitcnt vmcnt(0)" ::: "memory");
        }
        SB0();
        PH_MFMA(1)
        __builtin_amdgcn_s_barrier();                       // buf[d^1] ready for t+1
    }

    // epilogue: D row = 4*(lane>>4)+j, col = lane&15
    const int orow0 = row0 + wr * 128 + ((lane >> 4) << 2);
    const int ocol0 = col0 + wc * 64 + frow;
#pragma unroll
    for (int mi = 0; mi < 8; ++mi) {
#pragma unroll
        for (int ni = 0; ni < 4; ++ni) {
#pragma unroll
            for (int j = 0; j < 4; ++j) {
                const int rr = orow0 + mi * 16 + j;
                const int cc = ocol0 + ni * 16;
                C[(size_t)rr * N + cc] = acc[mi][ni][j] * cscale;
            }
        }
    }
}

// ---------------------------------------------------------------------------
// row softmax over f32 S (already scaled /32), in place: writes normalized
// P = exp(s-m)/sum as f16 at the same row base (row stride ncols f32 slots).
__global__ __launch_bounds__(256) void softmax_inplace(
    float* __restrict__ S, int ncols) {
    const int row = blockIdx.x;
    float* srow = S + (size_t)row * ncols;
    const int t = threadIdx.x;

    float x[16];
#pragma unroll
    for (int q = 0; q < 4; ++q) {
        float4 v = *(float4*)(srow + t * 16 + q * 4);
        x[q * 4 + 0] = v.x; x[q * 4 + 1] = v.y;
        x[q * 4 + 2] = v.z; x[q * 4 + 3] = v.w;
    }
    float m = x[0];
#pragma unroll
    for (int j = 1; j < 16; ++j) m = fmaxf(m, x[j]);
#pragma unroll
    for (int off = 32; off; off >>= 1) m = fmaxf(m, __shfl_xor(m, off));
    __shared__ float redm[4];
    if ((t & 63) == 0) redm[t >> 6] = m;
    __syncthreads();
    m = fmaxf(fmaxf(redm[0], redm[1]), fmaxf(redm[2], redm[3]));

    float s = 0.0f;
#pragma unroll
    for (int j = 0; j < 16; ++j) {
        x[j] = __expf(x[j] - m);
        s += x[j];
    }
#pragma unroll
    for (int off = 32; off; off >>= 1) s += __shfl_xor(s, off);
    __shared__ float reds[4];
    if ((t & 63) == 0) reds[t >> 6] = s;
    __syncthreads();
    s = reds[0] + reds[1] + reds[2] + reds[3];
    const float inv = 1.0f / s;

    _Float16* prow = (_Float16*)srow;
    half8 o0, o1;
#pragma unroll
    for (int j = 0; j < 8; ++j) {
        o0[j] = (_Float16)(x[j] * inv);
        o1[j] = (_Float16)(x[8 + j] * inv);
    }
    __syncthreads();
    *(half8*)(prow + t * 16)     = o0;
    *(half8*)(prow + t * 16 + 8) = o1;
}

// ---------------------------------------------------------------------------
extern "C" void kernel_launch(void* const* d_in, const int* in_sizes, int n_in,
                              void* d_out, int out_size, void* d_ws, size_t ws_size,
                              hipStream_t stream) {
    const float* x1 = (const float*)d_in[0];
    const float* x2 = (const float*)d_in[1];
    const float* Wq = (const float*)d_in[2];
    const float* Wk = (const float*)d_in[3];
    const float* Wv = (const float*)d_in[4];
    float* out = (float*)d_out;

    const int NQ = 4096, NKV = 4096, D = 1024;

    char* ws = (char*)d_ws;
    float*    S     = (float*)ws;                       //   0..64  f32 scores -> f16 P
    _Float16* x1cat = (_Float16*)(ws);                  //   0..24  [4096][3072] A-style
    _Float16* x2cat = (_Float16*)(ws + (24u  << 20));   //  24..48  A-style
    _Float16* Wqct  = (_Float16*)(ws + (48u  << 20));   //  48..54  B-style
    _Float16* Wkct  = (_Float16*)(ws + (54u  << 20));   //  54..60
    _Float16* Wvct  = (_Float16*)(ws + (60u  << 20));   //  60..66
    _Float16* Qcat  = (_Float16*)(ws + (66u  << 20));   //  66..90  A-style
    _Float16* Kcat  = (_Float16*)(ws + (90u  << 20));   //  90..114 B-style
    _Float16* Vt    = (_Float16*)(ws + (114u << 20));   // 114..122 [1024][4096] f16

    split_cast_a<<<(NQ * D) / 1024, 256, 0, stream>>>(x1, x1cat, D, NQ * D);
    split_cast_a<<<(NKV * D) / 1024, 256, 0, stream>>>(x2, x2cat, D, NKV * D);
    dim3 tb(32, 8), tg(D / 32, D / 32);
    transpose_split_b<<<tg, tb, 0, stream>>>(Wq, Wqct, D);
    transpose_split_b<<<tg, tb, 0, stream>>>(Wk, Wkct, D);
    transpose_split_b<<<tg, tb, 0, stream>>>(Wv, Wvct, D);

    gemm_bt<4><<<dim3(D / 128, NQ  / 128), 256, 0, stream>>>(x1cat, Wqct, Qcat, NQ,  D, 3 * D, 3 * D, 3 * D, 1.0f);
    gemm_bt<5><<<dim3(D / 128, NKV / 128), 256, 0, stream>>>(x2cat, Wkct, Kcat, NKV, D, 3 * D, 3 * D, 3 * D, 1.0f);
    gemm_bt<1><<<dim3(D / 128, NKV / 128), 256, 0, stream>>>(x2cat, Wvct, Vt,   NKV, D, 3 * D, 3 * D, 3 * D, 1.0f);

    // scores on the 256^2 8-phase kernel (16x16 = 256 blocks = 1/CU)
    gemm256_bt_f32<<<dim3(NKV / 256, NQ / 256), 512, 0, stream>>>(
        Qcat, Kcat, S, NQ, NKV, 3 * D, 3 * D, 3 * D, 1.0f / 32.0f);

    softmax_inplace<<<NQ, 256, 0, stream>>>(S, NKV);

    gemm_bt<3><<<dim3(D / 128, NQ / 128), 256, 0, stream>>>((const _Float16*)S, Vt, out, NQ, D, NKV, 2 * NKV, NKV, 1.0f);
}